// Round 12
// baseline (1471.484 us; speedup 1.0000x reference)
//
#include <hip/hip_runtime.h>
#include <hip/hip_bf16.h>

typedef __bf16 bf16;
typedef __bf16 bf16x4 __attribute__((ext_vector_type(4)));
typedef float  f32x4  __attribute__((ext_vector_type(4)));

#define NN 4096
#define KK 16
#define CC 128
#define BN_TOT 16384

// ---------------------------------------------------------------------------
// K1: Y = A(f32) @ W^T(f32) + b (fp32 out) + bn partials. LDS bf16 tiles.
// ---------------------------------------------------------------------------
__global__ __launch_bounds__(128) void k_lin_np(
    const float* __restrict__ A, const float* __restrict__ W,
    const float* __restrict__ bias, float* __restrict__ Y,
    float* __restrict__ partial) {
  __shared__ bf16 AS[64][132];
  __shared__ bf16 WS[128][132];
  int tid = threadIdx.x;
  int r0 = blockIdx.x * 64;
  for (int idx = tid; idx < 64 * 32; idx += 128) {
    int r = idx >> 5, c4 = idx & 31;
    f32x4 v = *(const f32x4*)(A + (r0 + r) * CC + c4 * 4);
    bf16x4 o;
    for (int i = 0; i < 4; i++) o[i] = (bf16)v[i];
    *(bf16x4*)(&AS[r][c4 * 4]) = o;
  }
  for (int idx = tid; idx < 128 * 32; idx += 128) {
    int r = idx >> 5, c4 = idx & 31;
    f32x4 v = *(const f32x4*)(W + r * CC + c4 * 4);
    bf16x4 o;
    for (int i = 0; i < 4; i++) o[i] = (bf16)v[i];
    *(bf16x4*)(&WS[r][c4 * 4]) = o;
  }
  __syncthreads();
  int j = tid;
  float bj = bias[j];
  float s1 = 0.f, s2 = 0.f;
  for (int rt = 0; rt < 4; rt++) {
    float acc[16];
    for (int r = 0; r < 16; r++) acc[r] = bj;
    for (int c4 = 0; c4 < 32; c4++) {
      bf16x4 w4 = *(const bf16x4*)(&WS[j][c4 * 4]);
      float w0 = (float)w4[0], w1 = (float)w4[1], w2 = (float)w4[2], w3 = (float)w4[3];
      for (int r = 0; r < 16; r++) {
        bf16x4 s = *(const bf16x4*)(&AS[rt * 16 + r][c4 * 4]);
        acc[r] += (float)s[0] * w0 + (float)s[1] * w1 + (float)s[2] * w2 + (float)s[3] * w3;
      }
    }
    for (int r = 0; r < 16; r++) {
      float v = acc[r];
      Y[(r0 + rt * 16 + r) * CC + j] = v;
      s1 += v; s2 += v * v;
    }
  }
  partial[blockIdx.x * 256 + j] = s1;
  partial[blockIdx.x * 256 + 128 + j] = s2;
}

// ---------------------------------------------------------------------------
__global__ __launch_bounds__(256) void k_finalize(
    const float* __restrict__ partial, const float* __restrict__ g,
    const float* __restrict__ b, float* __restrict__ stats, int NB) {
  __shared__ float sh[2][256];
  int t = threadIdx.x, c = t & 127, h = t >> 7;
  float s1 = 0.f, s2 = 0.f;
  for (int blk = h * (NB / 2); blk < (h + 1) * (NB / 2); blk++) {
    s1 += partial[blk * 256 + c];
    s2 += partial[blk * 256 + 128 + c];
  }
  sh[0][t] = s1; sh[1][t] = s2;
  __syncthreads();
  if (t < 128) {
    s1 = sh[0][t] + sh[0][t + 128];
    s2 = sh[1][t] + sh[1][t + 128];
    float mean = s1 * (1.0f / BN_TOT);
    float var  = s2 * (1.0f / BN_TOT) - mean * mean;
    float r = rsqrtf(var + 1e-5f);
    float sc = g[t] * r;
    stats[t] = sc;
    stats[128 + t] = b[t] - mean * sc;
  }
}

// ---------------------------------------------------------------------------
// K3: x = relu(bn2(y2)); q/k/v = x @ W^T (bf16 out to ws).
// ---------------------------------------------------------------------------
__global__ __launch_bounds__(128) void k_qkv(
    const float* __restrict__ Y, const float* __restrict__ stats,
    const float* __restrict__ Wq, const float* __restrict__ Wk, const float* __restrict__ Wv,
    bf16* __restrict__ Qo, bf16* __restrict__ Ko, bf16* __restrict__ Vo) {
  __shared__ bf16 AS[64][132];
  __shared__ bf16 WS[128][132];
  int tid = threadIdx.x;
  int r0 = blockIdx.x * 64;
  for (int idx = tid; idx < 64 * 32; idx += 128) {
    int r = idx >> 5, c4 = idx & 31;
    f32x4 y  = *(const f32x4*)(Y + (r0 + r) * CC + c4 * 4);
    f32x4 sc = *(const f32x4*)(stats + c4 * 4);
    f32x4 sf = *(const f32x4*)(stats + 128 + c4 * 4);
    bf16x4 o;
    for (int i = 0; i < 4; i++) o[i] = (bf16)fmaxf(y[i] * sc[i] + sf[i], 0.f);
    *(bf16x4*)(&AS[r][c4 * 4]) = o;
  }
  const float* Ws[3] = {Wq, Wk, Wv};
  bf16* Os[3] = {Qo, Ko, Vo};
  int j = tid;
  for (int m = 0; m < 3; m++) {
    __syncthreads();
    for (int idx = tid; idx < 128 * 32; idx += 128) {
      int r = idx >> 5, c4 = idx & 31;
      f32x4 v = *(const f32x4*)(Ws[m] + r * CC + c4 * 4);
      bf16x4 o;
      for (int i = 0; i < 4; i++) o[i] = (bf16)v[i];
      *(bf16x4*)(&WS[r][c4 * 4]) = o;
    }
    __syncthreads();
    for (int rt = 0; rt < 4; rt++) {
      float acc[16];
      for (int r = 0; r < 16; r++) acc[r] = 0.f;
      for (int c4 = 0; c4 < 32; c4++) {
        bf16x4 w4 = *(const bf16x4*)(&WS[j][c4 * 4]);
        float w0 = (float)w4[0], w1 = (float)w4[1], w2 = (float)w4[2], w3 = (float)w4[3];
        for (int r = 0; r < 16; r++) {
          bf16x4 s = *(const bf16x4*)(&AS[rt * 16 + r][c4 * 4]);
          acc[r] += (float)s[0] * w0 + (float)s[1] * w1 + (float)s[2] * w2 + (float)s[3] * w3;
        }
      }
      for (int r = 0; r < 16; r++)
        Os[m][(r0 + rt * 16 + r) * CC + j] = (bf16)acc[r];
    }
  }
}

// ---------------------------------------------------------------------------
// K4: attention core. One point/block, 128 threads. fp32 LDS for H/T1.
// ---------------------------------------------------------------------------
__global__ __launch_bounds__(128) void k_attn(
    const bf16* __restrict__ Q, const bf16* __restrict__ Kf, const bf16* __restrict__ Vf,
    const int* __restrict__ knn, const float* __restrict__ pose,
    const float* __restrict__ d_w1, const float* __restrict__ d_b1,
    const float* __restrict__ d_w2, const float* __restrict__ d_b2,
    const float* __restrict__ g_w1, const float* __restrict__ g_b1,
    const float* __restrict__ g_w2, const float* __restrict__ g_b2,
    float* __restrict__ Rs) {
  __shared__ float H[16][128];
  __shared__ float T1[16][128];
  __shared__ bf16  WS[128][132];
  __shared__ float PoseS[64];
  __shared__ int   IDX[16];

  int tid = threadIdx.x, gp = blockIdx.x, b = gp >> 12;
  if (tid < 16) IDX[tid] = knn[gp * KK + tid];
  if (tid < 64) PoseS[tid] = pose[gp * 64 + tid];
  float qreg = (float)Q[gp * CC + tid];
  __syncthreads();

  float vvreg[16];
  for (int k = 0; k < 16; k++) {
    int grow = (b << 12) + IDX[k];
    H[k][tid] = (float)Kf[grow * CC + tid];
    vvreg[k]  = (float)Vf[grow * CC + tid];
  }
  {
    f32x4 w = *(const f32x4*)(d_w1 + tid * 4);
    float bb = d_b1[tid];
    for (int k = 0; k < 16; k++) {
      float p0 = PoseS[k * 4 + 0], p1 = PoseS[k * 4 + 1];
      float p2 = PoseS[k * 4 + 2], p3 = PoseS[k * 4 + 3];
      T1[k][tid] = fmaxf(p0 * w[0] + p1 * w[1] + p2 * w[2] + p3 * w[3] + bb, 0.f);
    }
  }
  auto stageW = [&](const float* __restrict__ Wg) {
    for (int idx = tid; idx < 128 * 32; idx += 128) {
      int r = idx >> 5, c4 = idx & 31;
      f32x4 v = *(const f32x4*)(Wg + r * CC + c4 * 4);
      bf16x4 o;
      for (int i = 0; i < 4; i++) o[i] = (bf16)v[i];
      *(bf16x4*)(&WS[r][c4 * 4]) = o;
    }
  };
  auto gemmRows = [&](float (*SRC)[128], const float* bias, float* out16) {
    float bb = bias[tid];
    for (int k = 0; k < 16; k++) out16[k] = bb;
    for (int m4 = 0; m4 < 32; m4++) {
      bf16x4 w4 = *(const bf16x4*)(&WS[tid][m4 * 4]);
      float w0 = (float)w4[0], w1 = (float)w4[1], w2 = (float)w4[2], w3 = (float)w4[3];
      for (int k = 0; k < 16; k++) {
        f32x4 s = *(const f32x4*)(&SRC[k][m4 * 4]);
        out16[k] += s[0] * w0 + s[1] * w1 + s[2] * w2 + s[3] * w3;
      }
    }
  };

  __syncthreads();
  stageW(d_w2);
  __syncthreads();
  float tmp16[16];
  gemmRows(T1, d_b2, tmp16);               // pos for own column
  for (int k = 0; k < 16; k++) {
    H[k][tid] = qreg - H[k][tid] + tmp16[k];   // h = q - kk + pos
    vvreg[k] += tmp16[k];                      // vv + pos
  }
  __syncthreads();
  stageW(g_w1);
  __syncthreads();
  gemmRows(H, g_b1, tmp16);                // pre-relu t
  for (int k = 0; k < 16; k++) T1[k][tid] = fmaxf(tmp16[k], 0.f);
  __syncthreads();
  stageW(g_w2);
  __syncthreads();
  gemmRows(T1, g_b2, tmp16);               // attn logits (own column)
  const float sm = 0.08838834764831845f;   // 1/sqrt(128)
  float mx = -1e30f;
  for (int k = 0; k < 16; k++) { tmp16[k] *= sm; mx = fmaxf(mx, tmp16[k]); }
  float s = 0.f;
  for (int k = 0; k < 16; k++) { tmp16[k] = __expf(tmp16[k] - mx); s += tmp16[k]; }
  float rs = 1.0f / s, acc = 0.f;
  for (int k = 0; k < 16; k++) acc += tmp16[k] * rs * vvreg[k];
  Rs[gp * CC + tid] = acc;
}

// ---------------------------------------------------------------------------
// K5: y1 = res(f32) @ c1_w^T(f32) + c1_b + bn partials.
// ---------------------------------------------------------------------------
__global__ __launch_bounds__(128) void k_lin_res(
    const float* __restrict__ A, const float* __restrict__ W,
    const float* __restrict__ bias, float* __restrict__ Y,
    float* __restrict__ partial) {
  __shared__ bf16 AS[64][132];
  __shared__ bf16 WS[128][132];
  int tid = threadIdx.x;
  int r0 = blockIdx.x * 64;
  for (int idx = tid; idx < 64 * 32; idx += 128) {
    int r = idx >> 5, c4 = idx & 31;
    f32x4 v = *(const f32x4*)(A + (r0 + r) * CC + c4 * 4);
    bf16x4 o;
    for (int i = 0; i < 4; i++) o[i] = (bf16)v[i];
    *(bf16x4*)(&AS[r][c4 * 4]) = o;
  }
  for (int idx = tid; idx < 128 * 32; idx += 128) {
    int r = idx >> 5, c4 = idx & 31;
    f32x4 v = *(const f32x4*)(W + r * CC + c4 * 4);
    bf16x4 o;
    for (int i = 0; i < 4; i++) o[i] = (bf16)v[i];
    *(bf16x4*)(&WS[r][c4 * 4]) = o;
  }
  __syncthreads();
  int j = tid;
  float bj = bias[j];
  float s1 = 0.f, s2 = 0.f;
  for (int rt = 0; rt < 4; rt++) {
    float acc[16];
    for (int r = 0; r < 16; r++) acc[r] = bj;
    for (int c4 = 0; c4 < 32; c4++) {
      bf16x4 w4 = *(const bf16x4*)(&WS[j][c4 * 4]);
      float w0 = (float)w4[0], w1 = (float)w4[1], w2 = (float)w4[2], w3 = (float)w4[3];
      for (int r = 0; r < 16; r++) {
        bf16x4 s = *(const bf16x4*)(&AS[rt * 16 + r][c4 * 4]);
        acc[r] += (float)s[0] * w0 + (float)s[1] * w1 + (float)s[2] * w2 + (float)s[3] * w3;
      }
    }
    for (int r = 0; r < 16; r++) {
      float v = acc[r];
      Y[(r0 + rt * 16 + r) * CC + j] = v;
      s1 += v; s2 += v * v;
    }
  }
  partial[blockIdx.x * 256 + j] = s1;
  partial[blockIdx.x * 256 + 128 + j] = s2;
}

// ---------------------------------------------------------------------------
// K7: out = relu(bn1(y1)) + new_points   (fp32 out!)
// ---------------------------------------------------------------------------
__global__ __launch_bounds__(256) void k_out(
    const float* __restrict__ Y, const float* __restrict__ stats,
    const float* __restrict__ NP, float* __restrict__ Out) {
  int i0 = (blockIdx.x * 256 + threadIdx.x) * 4;
  int c0 = i0 & 127;
  f32x4 y  = *(const f32x4*)(Y + i0);
  f32x4 sc = *(const f32x4*)(stats + c0);
  f32x4 sh = *(const f32x4*)(stats + 128 + c0);
  f32x4 np = *(const f32x4*)(NP + i0);
  f32x4 o;
  for (int i = 0; i < 4; i++)
    o[i] = fmaxf(y[i] * sc[i] + sh[i], 0.f) + np[i];
  *(f32x4*)(Out + i0) = o;
}

// error reporter: plant fp32 code at a visible element
__global__ void k_code(float* out, float code) {
  if (threadIdx.x == 0) out[1000003] = code;
}

// ---------------------------------------------------------------------------
extern "C" void kernel_launch(void* const* d_in, const int* in_sizes, int n_in,
                              void* d_out, int out_size, void* d_ws, size_t ws_size,
                              hipStream_t stream) {
  static const int expect[22] = {
    1048576, 262144, 2097152, 16384, 16384, 16384,
    16384, 128, 16384, 128,
    512, 128, 16384, 128,
    16384, 128, 128, 128,
    16384, 128, 128, 128
  };
  if (n_in != 22) { k_code<<<1, 64, 0, stream>>>((float*)d_out, 4194304.f); return; }
  for (int i = 0; i < 22; i++)
    if (in_sizes[i] != expect[i]) {
      k_code<<<1, 64, 0, stream>>>((float*)d_out, 262144.f * (float)(i + 1));
      return;
    }

  const float* pose  = (const float*)d_in[0];
  const int*   knn   = (const int*)d_in[1];
  const float* np_   = (const float*)d_in[2];
  const float* wq    = (const float*)d_in[3];
  const float* wk    = (const float*)d_in[4];
  const float* wv    = (const float*)d_in[5];
  const float* g_w1  = (const float*)d_in[6];
  const float* g_b1  = (const float*)d_in[7];
  const float* g_w2  = (const float*)d_in[8];
  const float* g_b2  = (const float*)d_in[9];
  const float* d_w1  = (const float*)d_in[10];
  const float* d_b1  = (const float*)d_in[11];
  const float* d_w2  = (const float*)d_in[12];
  const float* d_b2  = (const float*)d_in[13];
  const float* c1_w  = (const float*)d_in[14];
  const float* c1_b  = (const float*)d_in[15];
  const float* bn1_g = (const float*)d_in[16];
  const float* bn1_b = (const float*)d_in[17];
  const float* c2_w  = (const float*)d_in[18];
  const float* c2_b  = (const float*)d_in[19];
  const float* bn2_g = (const float*)d_in[20];
  const float* bn2_b = (const float*)d_in[21];

  float* y2      = (float*)d_ws;            // 2,097,152 f32 (reused as y1)
  float* res     = y2 + 2097152;            // 2,097,152 f32
  bf16*  qf      = (bf16*)(res + 2097152);  // 3 x 2,097,152 bf16
  bf16*  kf      = qf + 2097152;
  bf16*  vf      = kf + 2097152;
  float* partial = (float*)(vf + 2097152);  // 256*256 f32
  float* stats2  = partial + 65536;
  float* stats1  = stats2 + 256;

  size_t NEED = (size_t)((char*)(stats1 + 256) - (char*)d_ws);
  if (ws_size < NEED) {
    k_code<<<1, 64, 0, stream>>>((float*)d_out, 2097152.f);
    return;
  }

  k_lin_np  <<<256, 128, 0, stream>>>(np_, c2_w, c2_b, y2, partial);
  k_finalize<<<1, 256, 0, stream>>>(partial, bn2_g, bn2_b, stats2, 256);
  k_qkv     <<<256, 128, 0, stream>>>(y2, stats2, wq, wk, wv, qf, kf, vf);
  k_attn    <<<16384, 128, 0, stream>>>(qf, kf, vf, knn, pose,
                                        d_w1, d_b1, d_w2, d_b2,
                                        g_w1, g_b1, g_w2, g_b2, res);
  k_lin_res <<<256, 128, 0, stream>>>(res, c1_w, c1_b, y2, partial);
  k_finalize<<<1, 256, 0, stream>>>(partial, bn1_g, bn1_b, stats1, 256);
  k_out     <<<2048, 256, 0, stream>>>(y2, stats1, np_, (float*)d_out);
}

// Round 13
// 538.683 us; speedup vs baseline: 2.7316x; 2.7316x over previous
//
#include <hip/hip_runtime.h>
#include <hip/hip_bf16.h>

typedef __bf16 bf16;
typedef __bf16 bf16x4 __attribute__((ext_vector_type(4)));
typedef __bf16 bf16x8 __attribute__((ext_vector_type(8)));
typedef float  f32x4  __attribute__((ext_vector_type(4)));

#define NN 4096
#define KK 16
#define CC 128
#define BN_TOT 16384

// ---------------------------------------------------------------------------
// K1: Y = A(f32) @ W^T(f32) + b (fp32 out) + bn partials. LDS bf16 tiles.
// ---------------------------------------------------------------------------
__global__ __launch_bounds__(128) void k_lin_np(
    const float* __restrict__ A, const float* __restrict__ W,
    const float* __restrict__ bias, float* __restrict__ Y,
    float* __restrict__ partial) {
  __shared__ bf16 AS[64][132];
  __shared__ bf16 WS[128][132];
  int tid = threadIdx.x;
  int r0 = blockIdx.x * 64;
  for (int idx = tid; idx < 64 * 32; idx += 128) {
    int r = idx >> 5, c4 = idx & 31;
    f32x4 v = *(const f32x4*)(A + (r0 + r) * CC + c4 * 4);
    bf16x4 o;
    for (int i = 0; i < 4; i++) o[i] = (bf16)v[i];
    *(bf16x4*)(&AS[r][c4 * 4]) = o;
  }
  for (int idx = tid; idx < 128 * 32; idx += 128) {
    int r = idx >> 5, c4 = idx & 31;
    f32x4 v = *(const f32x4*)(W + r * CC + c4 * 4);
    bf16x4 o;
    for (int i = 0; i < 4; i++) o[i] = (bf16)v[i];
    *(bf16x4*)(&WS[r][c4 * 4]) = o;
  }
  __syncthreads();
  int j = tid;
  float bj = bias[j];
  float s1 = 0.f, s2 = 0.f;
  for (int rt = 0; rt < 4; rt++) {
    float acc[16];
    for (int r = 0; r < 16; r++) acc[r] = bj;
    for (int c4 = 0; c4 < 32; c4++) {
      bf16x4 w4 = *(const bf16x4*)(&WS[j][c4 * 4]);
      float w0 = (float)w4[0], w1 = (float)w4[1], w2 = (float)w4[2], w3 = (float)w4[3];
      for (int r = 0; r < 16; r++) {
        bf16x4 s = *(const bf16x4*)(&AS[rt * 16 + r][c4 * 4]);
        acc[r] += (float)s[0] * w0 + (float)s[1] * w1 + (float)s[2] * w2 + (float)s[3] * w3;
      }
    }
    for (int r = 0; r < 16; r++) {
      float v = acc[r];
      Y[(r0 + rt * 16 + r) * CC + j] = v;
      s1 += v; s2 += v * v;
    }
  }
  partial[blockIdx.x * 256 + j] = s1;
  partial[blockIdx.x * 256 + 128 + j] = s2;
}

// ---------------------------------------------------------------------------
__global__ __launch_bounds__(256) void k_finalize(
    const float* __restrict__ partial, const float* __restrict__ g,
    const float* __restrict__ b, float* __restrict__ stats, int NB) {
  __shared__ float sh[2][256];
  int t = threadIdx.x, c = t & 127, h = t >> 7;
  float s1 = 0.f, s2 = 0.f;
  for (int blk = h * (NB / 2); blk < (h + 1) * (NB / 2); blk++) {
    s1 += partial[blk * 256 + c];
    s2 += partial[blk * 256 + 128 + c];
  }
  sh[0][t] = s1; sh[1][t] = s2;
  __syncthreads();
  if (t < 128) {
    s1 = sh[0][t] + sh[0][t + 128];
    s2 = sh[1][t] + sh[1][t + 128];
    float mean = s1 * (1.0f / BN_TOT);
    float var  = s2 * (1.0f / BN_TOT) - mean * mean;
    float r = rsqrtf(var + 1e-5f);
    float sc = g[t] * r;
    stats[t] = sc;
    stats[128 + t] = b[t] - mean * sc;
  }
}

// ---------------------------------------------------------------------------
// K3: x = relu(bn2(y2)); q/k/v = x @ W^T (bf16 out to ws).
// ---------------------------------------------------------------------------
__global__ __launch_bounds__(128) void k_qkv(
    const float* __restrict__ Y, const float* __restrict__ stats,
    const float* __restrict__ Wq, const float* __restrict__ Wk, const float* __restrict__ Wv,
    bf16* __restrict__ Qo, bf16* __restrict__ Ko, bf16* __restrict__ Vo) {
  __shared__ bf16 AS[64][132];
  __shared__ bf16 WS[128][132];
  int tid = threadIdx.x;
  int r0 = blockIdx.x * 64;
  for (int idx = tid; idx < 64 * 32; idx += 128) {
    int r = idx >> 5, c4 = idx & 31;
    f32x4 y  = *(const f32x4*)(Y + (r0 + r) * CC + c4 * 4);
    f32x4 sc = *(const f32x4*)(stats + c4 * 4);
    f32x4 sf = *(const f32x4*)(stats + 128 + c4 * 4);
    bf16x4 o;
    for (int i = 0; i < 4; i++) o[i] = (bf16)fmaxf(y[i] * sc[i] + sf[i], 0.f);
    *(bf16x4*)(&AS[r][c4 * 4]) = o;
  }
  const float* Ws[3] = {Wq, Wk, Wv};
  bf16* Os[3] = {Qo, Ko, Vo};
  int j = tid;
  for (int m = 0; m < 3; m++) {
    __syncthreads();
    for (int idx = tid; idx < 128 * 32; idx += 128) {
      int r = idx >> 5, c4 = idx & 31;
      f32x4 v = *(const f32x4*)(Ws[m] + r * CC + c4 * 4);
      bf16x4 o;
      for (int i = 0; i < 4; i++) o[i] = (bf16)v[i];
      *(bf16x4*)(&WS[r][c4 * 4]) = o;
    }
    __syncthreads();
    for (int rt = 0; rt < 4; rt++) {
      float acc[16];
      for (int r = 0; r < 16; r++) acc[r] = 0.f;
      for (int c4 = 0; c4 < 32; c4++) {
        bf16x4 w4 = *(const bf16x4*)(&WS[j][c4 * 4]);
        float w0 = (float)w4[0], w1 = (float)w4[1], w2 = (float)w4[2], w3 = (float)w4[3];
        for (int r = 0; r < 16; r++) {
          bf16x4 s = *(const bf16x4*)(&AS[rt * 16 + r][c4 * 4]);
          acc[r] += (float)s[0] * w0 + (float)s[1] * w1 + (float)s[2] * w2 + (float)s[3] * w3;
        }
      }
      for (int r = 0; r < 16; r++)
        Os[m][(r0 + rt * 16 + r) * CC + j] = (bf16)acc[r];
    }
  }
}

// ---------------------------------------------------------------------------
// K4: MFMA attention core. 4 points/WG, one wave per point, 256 threads.
// A-frag layout: lane holds X[m=l&15][k=quad*8+j] per 32-wide kc chunk.
// D layout: lane l reg g holds D[row=quad*4+g][col=jb*16+(l&15)]  (m89).
// ---------------------------------------------------------------------------
__global__ __launch_bounds__(256) void k_attn(
    const bf16* __restrict__ Q, const bf16* __restrict__ Kf, const bf16* __restrict__ Vf,
    const int* __restrict__ knn, const float* __restrict__ pose,
    const float* __restrict__ d_w1, const float* __restrict__ d_b1,
    const float* __restrict__ d_w2, const float* __restrict__ d_b2,
    const float* __restrict__ g_w1, const float* __restrict__ g_b1,
    const float* __restrict__ g_w2, const float* __restrict__ g_b2,
    float* __restrict__ Rs) {
  __shared__ bf16  WS[64][132];     // weight half: rows n = half*64 + r
  __shared__ bf16  S[4][16][132];   // per-wave D->A roundtrip scratch
  __shared__ float PoseS[4][64];
  __shared__ int   IDX[4][16];

  int tid = threadIdx.x, w = tid >> 6, l = tid & 63, quad = l >> 4, col = l & 15;
  int gp = blockIdx.x * 4 + w;
  int b  = gp >> 12;

  if (l < 16) IDX[w][l] = knn[gp * KK + l];
  PoseS[w][l] = pose[gp * 64 + l];

  // vv in D layout (registers): vpos[jb][g] = V[knn[quad*4+g]][jb*16+col]
  float vpos[8][4];
  for (int g = 0; g < 4; g++) {
    int grow = (b << 12) + IDX[w][quad * 4 + g];
    const bf16* vr = Vf + grow * CC + col;
    for (int jb = 0; jb < 8; jb++) vpos[jb][g] = (float)vr[jb * 16];
  }

  // h1 = relu(pose @ d_w1^T + d_b1) directly in A layout: m = col (neighbor k)
  bf16x8 aA[4];
  {
    float p0 = PoseS[w][col * 4 + 0], p1 = PoseS[w][col * 4 + 1];
    float p2 = PoseS[w][col * 4 + 2], p3 = PoseS[w][col * 4 + 3];
    for (int kc = 0; kc < 4; kc++) {
      bf16x8 v;
      for (int j = 0; j < 8; j++) {
        int c = kc * 32 + quad * 8 + j;
        f32x4 wr = *(const f32x4*)(d_w1 + c * 4);
        v[j] = (bf16)fmaxf(p0 * wr[0] + p1 * wr[1] + p2 * wr[2] + p3 * wr[3] + d_b1[c], 0.f);
      }
      aA[kc] = v;
    }
  }

  auto stageW = [&](const float* __restrict__ Wg, int half) {
    for (int e = tid; e < 64 * 16; e += 256) {
      int r = e >> 4, c8 = e & 15;
      const float* p = Wg + (half * 64 + r) * CC + c8 * 8;
      f32x4 v0 = *(const f32x4*)p, v1 = *(const f32x4*)(p + 4);
      bf16x8 o;
      for (int i = 0; i < 4; i++) { o[i] = (bf16)v0[i]; o[i + 4] = (bf16)v1[i]; }
      *(bf16x8*)(&WS[r][c8 * 8]) = o;
    }
  };
  // D[jb] = bias + aA @ Wg^T  (two staged halves)
  auto mfmaStage = [&](bf16x8 a[4], const float* __restrict__ Wg,
                       const float* __restrict__ bias, f32x4 D[8]) {
    for (int jb = 0; jb < 8; jb++) {
      float bv = bias[jb * 16 + col];
      D[jb] = (f32x4){bv, bv, bv, bv};
    }
    for (int half = 0; half < 2; half++) {
      __syncthreads();
      stageW(Wg, half);
      __syncthreads();
      for (int jbh = 0; jbh < 4; jbh++) {
        int jb = half * 4 + jbh;
        for (int kc = 0; kc < 4; kc++) {
          bf16x8 bfrag = *(const bf16x8*)(&WS[jbh * 16 + col][kc * 32 + quad * 8]);
          D[jb] = __builtin_amdgcn_mfma_f32_16x16x32_bf16(a[kc], bfrag, D[jb], 0, 0, 0);
        }
      }
    }
  };

  f32x4 D[8];
  // pos = h1 @ d_w2^T + d_b2
  mfmaStage(aA, d_w2, d_b2, D);
  for (int jb = 0; jb < 8; jb++)
    for (int g = 0; g < 4; g++) {
      vpos[jb][g] += D[jb][g];                               // vv + pos
      S[w][quad * 4 + g][jb * 16 + col] = (bf16)D[jb][g];    // pos -> scratch
    }
  // h = q - kk + pos in A layout (m = col neighbor)
  {
    int grow = (b << 12) + IDX[w][col];
    for (int kc = 0; kc < 4; kc++) {
      int c0 = kc * 32 + quad * 8;
      bf16x8 kkv = *(const bf16x8*)(Kf + grow * CC + c0);
      bf16x8 qv  = *(const bf16x8*)(Q + gp * CC + c0);
      bf16x8 pv  = *(const bf16x8*)(&S[w][col][c0]);
      bf16x8 hv;
      for (int j = 0; j < 8; j++)
        hv[j] = (bf16)((float)qv[j] - (float)kkv[j] + (float)pv[j]);
      aA[kc] = hv;
    }
  }
  // t = relu(h @ g_w1^T + g_b1)
  mfmaStage(aA, g_w1, g_b1, D);
  for (int jb = 0; jb < 8; jb++)
    for (int g = 0; g < 4; g++)
      S[w][quad * 4 + g][jb * 16 + col] = (bf16)fmaxf(D[jb][g], 0.f);
  for (int kc = 0; kc < 4; kc++)
    aA[kc] = *(const bf16x8*)(&S[w][col][kc * 32 + quad * 8]);
  // logits = t @ g_w2^T + g_b2
  mfmaStage(aA, g_w2, g_b2, D);

  // softmax over k (4 regs x 4 quads) per channel; weighted vpos sum
  const float sm = 0.08838834764831845f;  // 1/sqrt(128)
  for (int jb = 0; jb < 8; jb++) {
    float z[4], m = -1e30f;
    for (int g = 0; g < 4; g++) { z[g] = D[jb][g] * sm; m = fmaxf(m, z[g]); }
    m = fmaxf(m, __shfl_xor(m, 16));
    m = fmaxf(m, __shfl_xor(m, 32));
    float s = 0.f, p = 0.f;
    for (int g = 0; g < 4; g++) {
      float e = __expf(z[g] - m);
      s += e; p += e * vpos[jb][g];
    }
    s += __shfl_xor(s, 16); s += __shfl_xor(s, 32);
    p += __shfl_xor(p, 16); p += __shfl_xor(p, 32);
    if (quad == 0) Rs[gp * CC + jb * 16 + col] = p / s;
  }
}

// ---------------------------------------------------------------------------
// K5: y1 = res(f32) @ c1_w^T(f32) + c1_b + bn partials.
// ---------------------------------------------------------------------------
__global__ __launch_bounds__(128) void k_lin_res(
    const float* __restrict__ A, const float* __restrict__ W,
    const float* __restrict__ bias, float* __restrict__ Y,
    float* __restrict__ partial) {
  __shared__ bf16 AS[64][132];
  __shared__ bf16 WS[128][132];
  int tid = threadIdx.x;
  int r0 = blockIdx.x * 64;
  for (int idx = tid; idx < 64 * 32; idx += 128) {
    int r = idx >> 5, c4 = idx & 31;
    f32x4 v = *(const f32x4*)(A + (r0 + r) * CC + c4 * 4);
    bf16x4 o;
    for (int i = 0; i < 4; i++) o[i] = (bf16)v[i];
    *(bf16x4*)(&AS[r][c4 * 4]) = o;
  }
  for (int idx = tid; idx < 128 * 32; idx += 128) {
    int r = idx >> 5, c4 = idx & 31;
    f32x4 v = *(const f32x4*)(W + r * CC + c4 * 4);
    bf16x4 o;
    for (int i = 0; i < 4; i++) o[i] = (bf16)v[i];
    *(bf16x4*)(&WS[r][c4 * 4]) = o;
  }
  __syncthreads();
  int j = tid;
  float bj = bias[j];
  float s1 = 0.f, s2 = 0.f;
  for (int rt = 0; rt < 4; rt++) {
    float acc[16];
    for (int r = 0; r < 16; r++) acc[r] = bj;
    for (int c4 = 0; c4 < 32; c4++) {
      bf16x4 w4 = *(const bf16x4*)(&WS[j][c4 * 4]);
      float w0 = (float)w4[0], w1 = (float)w4[1], w2 = (float)w4[2], w3 = (float)w4[3];
      for (int r = 0; r < 16; r++) {
        bf16x4 s = *(const bf16x4*)(&AS[rt * 16 + r][c4 * 4]);
        acc[r] += (float)s[0] * w0 + (float)s[1] * w1 + (float)s[2] * w2 + (float)s[3] * w3;
      }
    }
    for (int r = 0; r < 16; r++) {
      float v = acc[r];
      Y[(r0 + rt * 16 + r) * CC + j] = v;
      s1 += v; s2 += v * v;
    }
  }
  partial[blockIdx.x * 256 + j] = s1;
  partial[blockIdx.x * 256 + 128 + j] = s2;
}

// ---------------------------------------------------------------------------
// K7: out = relu(bn1(y1)) + new_points   (fp32 out)
// ---------------------------------------------------------------------------
__global__ __launch_bounds__(256) void k_out(
    const float* __restrict__ Y, const float* __restrict__ stats,
    const float* __restrict__ NP, float* __restrict__ Out) {
  int i0 = (blockIdx.x * 256 + threadIdx.x) * 4;
  int c0 = i0 & 127;
  f32x4 y  = *(const f32x4*)(Y + i0);
  f32x4 sc = *(const f32x4*)(stats + c0);
  f32x4 sh = *(const f32x4*)(stats + 128 + c0);
  f32x4 np = *(const f32x4*)(NP + i0);
  f32x4 o;
  for (int i = 0; i < 4; i++)
    o[i] = fmaxf(y[i] * sc[i] + sh[i], 0.f) + np[i];
  *(f32x4*)(Out + i0) = o;
}

__global__ void k_code(float* out, float code) {
  if (threadIdx.x == 0) out[1000003] = code;
}

// ---------------------------------------------------------------------------
extern "C" void kernel_launch(void* const* d_in, const int* in_sizes, int n_in,
                              void* d_out, int out_size, void* d_ws, size_t ws_size,
                              hipStream_t stream) {
  static const int expect[22] = {
    1048576, 262144, 2097152, 16384, 16384, 16384,
    16384, 128, 16384, 128,
    512, 128, 16384, 128,
    16384, 128, 128, 128,
    16384, 128, 128, 128
  };
  if (n_in != 22) { k_code<<<1, 64, 0, stream>>>((float*)d_out, 4194304.f); return; }
  for (int i = 0; i < 22; i++)
    if (in_sizes[i] != expect[i]) {
      k_code<<<1, 64, 0, stream>>>((float*)d_out, 262144.f * (float)(i + 1));
      return;
    }

  const float* pose  = (const float*)d_in[0];
  const int*   knn   = (const int*)d_in[1];
  const float* np_   = (const float*)d_in[2];
  const float* wq    = (const float*)d_in[3];
  const float* wk    = (const float*)d_in[4];
  const float* wv    = (const float*)d_in[5];
  const float* g_w1  = (const float*)d_in[6];
  const float* g_b1  = (const float*)d_in[7];
  const float* g_w2  = (const float*)d_in[8];
  const float* g_b2  = (const float*)d_in[9];
  const float* d_w1  = (const float*)d_in[10];
  const float* d_b1  = (const float*)d_in[11];
  const float* d_w2  = (const float*)d_in[12];
  const float* d_b2  = (const float*)d_in[13];
  const float* c1_w  = (const float*)d_in[14];
  const float* c1_b  = (const float*)d_in[15];
  const float* bn1_g = (const float*)d_in[16];
  const float* bn1_b = (const float*)d_in[17];
  const float* c2_w  = (const float*)d_in[18];
  const float* c2_b  = (const float*)d_in[19];
  const float* bn2_g = (const float*)d_in[20];
  const float* bn2_b = (const float*)d_in[21];

  float* y2      = (float*)d_ws;            // 2,097,152 f32 (reused as y1)
  float* res     = y2 + 2097152;            // 2,097,152 f32
  bf16*  qf      = (bf16*)(res + 2097152);  // 3 x 2,097,152 bf16
  bf16*  kf      = qf + 2097152;
  bf16*  vf      = kf + 2097152;
  float* partial = (float*)(vf + 2097152);  // 256*256 f32
  float* stats2  = partial + 65536;
  float* stats1  = stats2 + 256;

  size_t NEED = (size_t)((char*)(stats1 + 256) - (char*)d_ws);
  if (ws_size < NEED) {
    k_code<<<1, 64, 0, stream>>>((float*)d_out, 2097152.f);
    return;
  }

  k_lin_np  <<<256, 128, 0, stream>>>(np_, c2_w, c2_b, y2, partial);
  k_finalize<<<1, 256, 0, stream>>>(partial, bn2_g, bn2_b, stats2, 256);
  k_qkv     <<<256, 128, 0, stream>>>(y2, stats2, wq, wk, wv, qf, kf, vf);
  k_attn    <<<4096, 256, 0, stream>>>(qf, kf, vf, knn, pose,
                                       d_w1, d_b1, d_w2, d_b2,
                                       g_w1, g_b1, g_w2, g_b2, res);
  k_lin_res <<<256, 128, 0, stream>>>(res, c1_w, c1_b, y2, partial);
  k_finalize<<<1, 256, 0, stream>>>(partial, bn1_g, bn1_b, stats1, 256);
  k_out     <<<2048, 256, 0, stream>>>(y2, stats1, np_, (float*)d_out);
}